// Round 9
// baseline (427.670 us; speedup 1.0000x reference)
//
#include <hip/hip_runtime.h>

#define S 3072
#define D 512
#define H 8

constexpr float LN_EPS = 1e-6f;

typedef __attribute__((ext_vector_type(2))) _Float16 f16x2;
typedef __attribute__((ext_vector_type(8))) _Float16 f16x8;  // 8 f16 = 4 VGPRs
typedef __attribute__((ext_vector_type(4))) float f32x4;     // MFMA C/D frag

// v_cvt_pkrtz_f16_f32: pack 2 fp32 -> 2 fp16 (RTZ), bit_cast to our f16x2
__device__ __forceinline__ f16x2 cvt_pk(float lo, float hi) {
    return __builtin_bit_cast(f16x2, __builtin_amdgcn_cvt_pkrtz(lo, hi));
}

// -------------------- K1: QKV projection --------------------
// x[S,D] @ {Wq,Wk,Wv}[D,512] + b -> fp16 Q,K in [H][S][64] (Q pre-scaled by
// 1/16 = 1/sqrt(64)/2, folding entmax's /2 into the logits) and fp16 V^T in
// [H][64][S]. grid (S/8, 6), block 256.
__global__ void qkv_kernel(const float* __restrict__ x,
                           const float* __restrict__ Wq, const float* __restrict__ bq,
                           const float* __restrict__ Wk, const float* __restrict__ bk,
                           const float* __restrict__ Wv, const float* __restrict__ bv,
                           _Float16* __restrict__ Qb, _Float16* __restrict__ Kb,
                           _Float16* __restrict__ Vt) {
    const int rb = blockIdx.x;
    const int cb = blockIdx.y;
    const int t  = threadIdx.x;
    const int r0 = rb * 8;
    const int gc = cb * 256 + t;     // 0..1535
    const int m  = gc >> 9;          // 0:Q 1:K 2:V
    const int cc = gc & 511;
    const float* W    = (m == 0) ? Wq : (m == 1) ? Wk : Wv;
    const float* bias = (m == 0) ? bq : (m == 1) ? bk : bv;
    const float4* xf4 = (const float4*)(x + (size_t)r0 * D);

    float acc[8];
#pragma unroll
    for (int r = 0; r < 8; ++r) acc[r] = 0.f;

    for (int k4 = 0; k4 < D / 4; ++k4) {
        float w0 = W[(k4 * 4 + 0) * 512 + cc];
        float w1 = W[(k4 * 4 + 1) * 512 + cc];
        float w2 = W[(k4 * 4 + 2) * 512 + cc];
        float w3 = W[(k4 * 4 + 3) * 512 + cc];
#pragma unroll
        for (int r = 0; r < 8; ++r) {
            float4 xv = xf4[r * (D / 4) + k4];   // uniform -> s_load broadcast
            acc[r] += xv.x * w0 + xv.y * w1 + xv.z * w2 + xv.w * w3;
        }
    }
    const float b = bias[cc];
    const int h = cc >> 6, d = cc & 63;
    const float scale = (m == 0) ? 0.0625f : 1.0f;   // 1/sqrt(64) * 1/2 (w-space)
#pragma unroll
    for (int r = 0; r < 8; ++r) {
        float val = (acc[r] + b) * scale;
        if (m == 0)      Qb[(((size_t)h * S + (r0 + r)) << 6) + d] = (_Float16)val;
        else if (m == 1) Kb[(((size_t)h * S + (r0 + r)) << 6) + d] = (_Float16)val;
        else             Vt[((size_t)h * 64 + d) * S + (r0 + r)]   = (_Float16)val;
    }
}

// -------------------- K2: fused logits + entmax-1.5 + PV --------------------
// 512 threads = 8 waves; block owns 16 q-rows x full S; wave w owns k-slice
// [w*384, w*384+384). Q pre-scaled so MFMA emits w = logit/2 directly.
// Pass A: 48 MFMA, keep w packed fp16 (zw, 48 VGPRs); per-row max/sum/sumsq
// via fdot2 -> closed-form full-support init. Pass B: register-only Michelot
// iterations with v_pk_* + v_dot2_f32_f16, single barrier/iter (sred ping-pong).
// Final: P -> fp32 attn (nontemporal) + fp16 plds transpose -> fp16 PV MFMA ->
// cross-wave sum -> AO.
__global__ __launch_bounds__(512, 2) void fused_attn_kernel(
        const _Float16* __restrict__ Qb, const _Float16* __restrict__ Kb,
        const _Float16* __restrict__ Vt, float* __restrict__ attn,
        float* __restrict__ AO) {
    __shared__ float sred[2][8][16][3];      // ping-pong per-wave per-row stats
    __shared__ _Float16 plds[8][16][40];     // per-wave P transpose scratch
    __shared__ float pacc[8][16][64];        // per-wave PV partials
    const int bid = blockIdx.x;
    const int h = bid & 7, qt = bid >> 3;    // one head per XCD
    const int q0 = qt * 16;
    const int t = threadIdx.x;
    const int w = t >> 6, l = t & 63;
    const int lr = l & 15, lk = l >> 4;
    const int kbase = w * 384;

    const _Float16* Qh = Qb + ((size_t)h * S) * 64;
    const _Float16* Kh = Kb + ((size_t)h * S) * 64;
    const _Float16* Vh = Vt + (size_t)h * 64 * S;

    const f16x8 aq0 = *(const f16x8*)(Qh + (size_t)(q0 + lr) * 64 + lk * 8);
    const f16x8 aq1 = *(const f16x8*)(Qh + (size_t)(q0 + lr) * 64 + 32 + lk * 8);

    const f16x2 one2  = {(_Float16)1.f, (_Float16)1.f};
    const f16x2 zero2 = {(_Float16)0.f, (_Float16)0.f};
    const f16x2 big2  = {(_Float16)16384.f, (_Float16)16384.f};

    // ---- Pass A: logits once (already w-space); packed stats ----
    f16x2 zw[12][4];
    f16x2 m2[4];
    float s4[4] = {}, q4[4] = {};
#pragma unroll
    for (int r = 0; r < 4; ++r) m2[r] = (f16x2){(_Float16)-60000.f, (_Float16)-60000.f};
#pragma unroll
    for (int jp = 0; jp < 12; ++jp) {
        const _Float16* kp = Kh + (size_t)(kbase + jp * 32 + lr) * 64;
        f16x8 b00 = *(const f16x8*)(kp + lk * 8);
        f16x8 b01 = *(const f16x8*)(kp + 32 + lk * 8);
        f16x8 b10 = *(const f16x8*)(kp + 16 * 64 + lk * 8);
        f16x8 b11 = *(const f16x8*)(kp + 16 * 64 + 32 + lk * 8);
        f32x4 d0 = (f32x4){0.f, 0.f, 0.f, 0.f}, d1 = d0;
        d0 = __builtin_amdgcn_mfma_f32_16x16x32_f16(aq0, b00, d0, 0, 0, 0);
        d0 = __builtin_amdgcn_mfma_f32_16x16x32_f16(aq1, b01, d0, 0, 0, 0);
        d1 = __builtin_amdgcn_mfma_f32_16x16x32_f16(aq0, b10, d1, 0, 0, 0);
        d1 = __builtin_amdgcn_mfma_f32_16x16x32_f16(aq1, b11, d1, 0, 0, 0);
#pragma unroll
        for (int r = 0; r < 4; ++r) {
            f16x2 w2 = cvt_pk(d0[r], d1[r]);
            zw[jp][r] = w2;
            m2[r] = __builtin_elementwise_max(m2[r], w2);
            s4[r] = __builtin_amdgcn_fdot2(w2, one2, s4[r], false);
            q4[r] = __builtin_amdgcn_fdot2(w2, w2, q4[r], false);
        }
    }
    float m4[4];
#pragma unroll
    for (int r = 0; r < 4; ++r) m4[r] = fmaxf((float)m2[r][0], (float)m2[r][1]);
#pragma unroll
    for (int off = 1; off < 16; off <<= 1) {
#pragma unroll
        for (int r = 0; r < 4; ++r) {
            m4[r] = fmaxf(m4[r], __shfl_xor(m4[r], off, 64));
            s4[r] += __shfl_xor(s4[r], off, 64);
            q4[r] += __shfl_xor(q4[r], off, 64);
        }
    }
    if (lr == 0) {
#pragma unroll
        for (int r = 0; r < 4; ++r) {
            sred[0][w][lk * 4 + r][0] = m4[r];
            sred[0][w][lk * 4 + r][1] = s4[r];
            sred[0][w][lk * 4 + r][2] = q4[r];
        }
    }
    __syncthreads();

    // ---- closed-form full-support init (w-space) ----
    const float n = (float)S;
    float Tj;
    {
        float mj = -1e30f, sj = 0.f, qj = 0.f;
#pragma unroll
        for (int ww = 0; ww < 8; ++ww) {
            mj = fmaxf(mj, sred[0][ww][lr][0]);
            sj += sred[0][ww][lr][1];
            qj += sred[0][ww][lr][2];
        }
        float mean = sj * (1.f / n);
        float msq  = qj * (1.f / n);
        float ssv  = n * (msq - mean * mean);
        Tj = mean - sqrtf(fmaxf((1.f - ssv) / n, 0.f));
        Tj = fminf(fmaxf(Tj, mj - 1.0f), mj - 0.01f);
    }
    float T4[4];
#pragma unroll
    for (int r = 0; r < 4; ++r) T4[r] = __shfl(Tj, lk * 4 + r, 64);
    // no barrier: Pass B iter 0 writes sred[1], init read sred[0]

    // ---- Pass B: register-only packed Michelot iterations ----
    for (int it = 0; it < 8; ++it) {
        const int buf = (it + 1) & 1;
        f16x2 T2[4];
#pragma unroll
        for (int r = 0; r < 4; ++r) T2[r] = cvt_pk(T4[r], T4[r]);
        float f4[4] = {}, fp4[4] = {}, cn4[4] = {};
#pragma unroll
        for (int jp = 0; jp < 12; ++jp)
#pragma unroll
            for (int r = 0; r < 4; ++r) {
                f16x2 zc = __builtin_elementwise_max(zw[jp][r] - T2[r], zero2);
                f4[r]  = __builtin_amdgcn_fdot2(zc, zc, f4[r], false);
                fp4[r] = __builtin_amdgcn_fdot2(zc, one2, fp4[r], false);
                f16x2 g = __builtin_elementwise_min(zc * big2, one2);
                cn4[r] = __builtin_amdgcn_fdot2(g, one2, cn4[r], false);
            }
#pragma unroll
        for (int off = 1; off < 16; off <<= 1) {
#pragma unroll
            for (int r = 0; r < 4; ++r) {
                f4[r]  += __shfl_xor(f4[r],  off, 64);
                fp4[r] += __shfl_xor(fp4[r], off, 64);
                cn4[r] += __shfl_xor(cn4[r], off, 64);
            }
        }
        if (lr == 0) {
#pragma unroll
            for (int r = 0; r < 4; ++r) {
                sred[buf][w][lk * 4 + r][0] = f4[r];
                sred[buf][w][lk * 4 + r][1] = fp4[r];
                sred[buf][w][lk * 4 + r][2] = cn4[r];
            }
        }
        __syncthreads();
        float fj = 0.f, fpj = 0.f, cnj = 0.f;
#pragma unroll
        for (int ww = 0; ww < 8; ++ww) {
            fj  += sred[buf][ww][lr][0];
            fpj += sred[buf][ww][lr][1];
            cnj += sred[buf][ww][lr][2];
        }
        float ns   = fmaxf(cnj, 1.0f);
        float disc = fmaxf(fpj * fpj - ns * (fj - 1.0f), 0.f);
        float del  = (fpj - sqrtf(disc)) / ns;
#pragma unroll
        for (int r = 0; r < 4; ++r) T4[r] += __shfl(del, lk * 4 + r, 64);
        if (__all(fabsf(del) < 2e-6f)) break;   // block-uniform
    }

    // ---- Final: P -> attn (nontemporal) + fp16 plds transpose -> PV MFMA ----
    f16x2 T2[4];
#pragma unroll
    for (int r = 0; r < 4; ++r) T2[r] = cvt_pk(T4[r], T4[r]);
    f32x4 acc[4];
#pragma unroll
    for (int j = 0; j < 4; ++j) acc[j] = (f32x4){0.f, 0.f, 0.f, 0.f};
    float* arow = attn + ((size_t)h * S + q0) * S;
#pragma unroll
    for (int jp = 0; jp < 12; ++jp) {
#pragma unroll
        for (int r = 0; r < 4; ++r) {
            f16x2 zc = __builtin_elementwise_max(zw[jp][r] - T2[r], zero2);
            f16x2 p2 = zc * zc;
            const int row = lk * 4 + r;
            size_t cb = (size_t)row * S + kbase + jp * 32;
            __builtin_nontemporal_store((float)p2[0], &arow[cb + lr]);
            __builtin_nontemporal_store((float)p2[1], &arow[cb + 16 + lr]);
            plds[w][row][lr]      = p2[0];
            plds[w][row][16 + lr] = p2[1];
        }
        // same-wave LDS round-trip (compiler inserts lgkmcnt; no barrier)
        f16x8 a = *(const f16x8*)&plds[w][lr][lk * 8];
        const _Float16* vp = Vh + kbase + jp * 32 + lk * 8;
#pragma unroll
        for (int j = 0; j < 4; ++j) {
            f16x8 b = *(const f16x8*)(vp + (size_t)(j * 16 + lr) * S);
            acc[j] = __builtin_amdgcn_mfma_f32_16x16x32_f16(a, b, acc[j], 0, 0, 0);
        }
    }
    // cross-wave PV reduction
#pragma unroll
    for (int j = 0; j < 4; ++j)
#pragma unroll
        for (int r = 0; r < 4; ++r)
            pacc[w][lk * 4 + r][j * 16 + lr] = acc[j][r];
    __syncthreads();
    float* AOr = AO + ((size_t)h * S + q0) * 64;
#pragma unroll
    for (int u = 0; u < 2; ++u) {
        int idx = t + 512 * u;             // 0..1023
        int row = idx >> 6, col = idx & 63;
        float sum = 0.f;
#pragma unroll
        for (int ww = 0; ww < 8; ++ww) sum += pacc[ww][row][col];
        AOr[(size_t)row * 64 + col] = sum;
    }
}

// -------------------- K5: out-proj + residual + LayerNorm --------------------
// grid (S/4), block 256: 4 rows/block for 2x the wave count of S/8 (was
// latency-bound at 1.5 waves/SIMD).
__global__ void outproj_ln_kernel(const float* __restrict__ AO, const float* __restrict__ Wo,
                                  const float* __restrict__ bo, const float* __restrict__ x,
                                  const float* __restrict__ gamma, const float* __restrict__ beta,
                                  float* __restrict__ out) {
    __shared__ float red[8];
    const int rb = blockIdx.x;
    const int t  = threadIdx.x;
    const int s0 = rb * 4;
    float acc0[4] = {}, acc1[4] = {};
    const int c0 = t, c1 = t + 256;
    const float4* A0 = (const float4*)AO;
    for (int k4 = 0; k4 < 128; ++k4) {
        int k = k4 * 4;
        int h = k >> 6, d4 = (k & 63) >> 2;
        float w00 = Wo[(k + 0) * 512 + c0], w10 = Wo[(k + 0) * 512 + c1];
        float w01 = Wo[(k + 1) * 512 + c0], w11 = Wo[(k + 1) * 512 + c1];
        float w02 = Wo[(k + 2) * 512 + c0], w12 = Wo[(k + 2) * 512 + c1];
        float w03 = Wo[(k + 3) * 512 + c0], w13 = Wo[(k + 3) * 512 + c1];
#pragma unroll
        for (int r = 0; r < 4; ++r) {
            float4 a = A0[((size_t)h * S + s0 + r) * 16 + d4];   // uniform
            acc0[r] += a.x * w00 + a.y * w01 + a.z * w02 + a.w * w03;
            acc1[r] += a.x * w10 + a.y * w11 + a.z * w12 + a.w * w13;
        }
    }
    const float b0 = bo[c0], b1 = bo[c1];
    const float g0 = gamma[c0], g1 = gamma[c1];
    const float be0 = beta[c0], be1 = beta[c1];
    const int wave = t >> 6, lane = t & 63;
    for (int r = 0; r < 4; ++r) {
        float y0 = acc0[r] + b0 + x[(size_t)(s0 + r) * 512 + c0];
        float y1 = acc1[r] + b1 + x[(size_t)(s0 + r) * 512 + c1];
        float s = y0 + y1, qq = y0 * y0 + y1 * y1;
#pragma unroll
        for (int off = 32; off; off >>= 1) {
            s  += __shfl_down(s, off, 64);
            qq += __shfl_down(qq, off, 64);
        }
        __syncthreads();
        if (lane == 0) { red[wave * 2] = s; red[wave * 2 + 1] = qq; }
        __syncthreads();
        s  = red[0] + red[2] + red[4] + red[6];
        qq = red[1] + red[3] + red[5] + red[7];
        float mu  = s * (1.0f / 512.0f);
        float var = qq * (1.0f / 512.0f) - mu * mu;
        float inv = rsqrtf(var + LN_EPS);
        out[(size_t)(s0 + r) * 512 + c0] = (y0 - mu) * inv * g0 + be0;
        out[(size_t)(s0 + r) * 512 + c1] = (y1 - mu) * inv * g1 + be1;
    }
}

extern "C" void kernel_launch(void* const* d_in, const int* in_sizes, int n_in,
                              void* d_out, int out_size, void* d_ws, size_t ws_size,
                              hipStream_t stream) {
    const float* x     = (const float*)d_in[0];
    const float* Wq    = (const float*)d_in[1];
    const float* bq    = (const float*)d_in[2];
    const float* Wk    = (const float*)d_in[3];
    const float* bk    = (const float*)d_in[4];
    const float* Wv    = (const float*)d_in[5];
    const float* bv    = (const float*)d_in[6];
    const float* Wo    = (const float*)d_in[7];
    const float* bo    = (const float*)d_in[8];
    const float* gamma = (const float*)d_in[9];
    const float* beta  = (const float*)d_in[10];

    float* out  = (float*)d_out;
    float* attn = out + (size_t)S * D;          // tuple output #2

    _Float16* Qb = (_Float16*)d_ws;             // [H][S][64] fp16, pre-scaled 1/16
    _Float16* Kb = Qb + (size_t)H * S * 64;     // [H][S][64] fp16
    _Float16* Vt = Kb + (size_t)H * S * 64;     // [H][64][S] fp16 (transposed)
    float* AO = (float*)(Vt + (size_t)H * 64 * S);   // [H][S][64] f32

    qkv_kernel<<<dim3(S / 8, 6), 256, 0, stream>>>(x, Wq, bq, Wk, bk, Wv, bv, Qb, Kb, Vt);
    fused_attn_kernel<<<dim3((S / 16) * H), 512, 0, stream>>>(Qb, Kb, Vt, attn, AO);
    outproj_ln_kernel<<<dim3(S / 4), 256, 0, stream>>>(AO, Wo, bo, x, gamma, beta, out);
}